// Round 2
// baseline (773.661 us; speedup 1.0000x reference)
//
#include <hip/hip_runtime.h>
#include <hip/hip_bf16.h>
#include <stdint.h>

// Problem: C[8192,4096] = x[8192,2049] @ filters_real[4096,2049]^T  (fp32)
// (filters_imag is provably dead: Re(x*(a+bi)) = x*a for real x.)
//
// Strategy: hi/lo bf16 split -> bf16 MFMA GEMM over 3 K-segments:
//   C = x_hi@f_hi + x_hi@f_lo + x_lo@f_hi   (lo@lo term ~2^-32 rel, dropped)
// m97-structure GEMM: 128x128 tile, BK=32, 4 waves, mfma_f32_16x16x32_bf16,
// global_load_lds width-16 staging, XCD-bijective blockIdx swizzle.

#define KIN   2049
#define KPAD  2080            // 65 * 32, per-segment padded K
#define MDIM  8192
#define NDIM  4096
#define BM    128
#define BN    128
#define BK    32
#define NT_SEG (KPAD / BK)    // 65

typedef __bf16 bf16x8 __attribute__((ext_vector_type(8)));
typedef float  f32x4  __attribute__((ext_vector_type(4)));
using bf16 = __hip_bfloat16;

// ---------------- prep: fp32 -> (hi, lo) bf16, zero-padded to KPAD ----------
__global__ void split_hilo(const float* __restrict__ src, bf16* __restrict__ hi,
                           bf16* __restrict__ lo) {
  int c0 = (blockIdx.x * 256 + threadIdx.x) * 4;
  int r  = blockIdx.y;
  if (c0 >= KPAD) return;
#pragma unroll
  for (int u = 0; u < 4; ++u) {
    int c = c0 + u;
    if (c >= KPAD) break;
    float v = (c < KIN) ? src[(size_t)r * KIN + c] : 0.0f;
    bf16 hb = __float2bfloat16(v);
    float h = __bfloat162float(hb);
    bf16 lb = __float2bfloat16(v - h);
    hi[(size_t)r * KPAD + c] = hb;
    lo[(size_t)r * KPAD + c] = lb;
  }
}

// ---------------- main GEMM (m97 structure) ---------------------------------
__global__ __launch_bounds__(256, 2) void gemm_split(
    const bf16* __restrict__ A_hi, const bf16* __restrict__ A_lo,
    const bf16* __restrict__ B_hi, const bf16* __restrict__ B_lo,
    float* __restrict__ C) {
  __shared__ bf16 As[BM * BK];   // 8 KB, linear [row][k]
  __shared__ bf16 Bs[BN * BK];   // 8 KB

  // XCD-bijective swizzle: 2048 blocks, 8 XCDs, 256 contiguous tiles per XCD
  int wg  = blockIdx.x;
  int swz = (wg & 7) * ((int)gridDim.x >> 3) + (wg >> 3);
  int mt  = swz >> 5;            // 64 m-tiles
  int nt  = swz & 31;            // 32 n-tiles
  int brow = mt * BM;
  int bcol = nt * BN;

  int tid  = threadIdx.x;
  int wid  = tid >> 6;
  int lane = tid & 63;
  int wr = wid >> 1, wc = wid & 1;     // 2x2 wave grid, 64x64 per wave
  int lr = lane & 15, lk = lane >> 4;

  // per-thread staging indices (constant across K-loop)
  int e0   = tid * 8;                  // elements 0..2047
  int row0 = e0 >> 5, col0 = e0 & 31;
  int e1   = (256 + tid) * 8;
  int row1 = e1 >> 5, col1 = e1 & 31;

  f32x4 acc[4][4] = {};

  const bf16* Asegs[3] = { A_hi, A_hi, A_lo };
  const bf16* Bsegs[3] = { B_hi, B_lo, B_hi };

#pragma unroll 1
  for (int seg = 0; seg < 3; ++seg) {
    const bf16* Aseg = Asegs[seg];
    const bf16* Bseg = Bsegs[seg];
    const bf16* ga0base = Aseg + (size_t)(brow + row0) * KPAD + col0;
    const bf16* ga1base = Aseg + (size_t)(brow + row1) * KPAD + col1;
    const bf16* gb0base = Bseg + (size_t)(bcol + row0) * KPAD + col0;
    const bf16* gb1base = Bseg + (size_t)(bcol + row1) * KPAD + col1;

#pragma unroll 1
    for (int kt = 0; kt < NT_SEG; ++kt) {
      int kc = kt * BK;
      __builtin_amdgcn_global_load_lds(
          (const __attribute__((address_space(1))) void*)(ga0base + kc),
          (__attribute__((address_space(3))) void*)(&As[e0]), 16, 0, 0);
      __builtin_amdgcn_global_load_lds(
          (const __attribute__((address_space(1))) void*)(ga1base + kc),
          (__attribute__((address_space(3))) void*)(&As[e1]), 16, 0, 0);
      __builtin_amdgcn_global_load_lds(
          (const __attribute__((address_space(1))) void*)(gb0base + kc),
          (__attribute__((address_space(3))) void*)(&Bs[e0]), 16, 0, 0);
      __builtin_amdgcn_global_load_lds(
          (const __attribute__((address_space(1))) void*)(gb1base + kc),
          (__attribute__((address_space(3))) void*)(&Bs[e1]), 16, 0, 0);
      __syncthreads();   // compiler emits vmcnt(0) drain before barrier

      int k8 = lk * 8;
      bf16x8 af[4], bg[4];
#pragma unroll
      for (int i = 0; i < 4; ++i)
        af[i] = *reinterpret_cast<const bf16x8*>(&As[(wr * 64 + i * 16 + lr) * BK + k8]);
#pragma unroll
      for (int j = 0; j < 4; ++j)
        bg[j] = *reinterpret_cast<const bf16x8*>(&Bs[(wc * 64 + j * 16 + lr) * BK + k8]);
#pragma unroll
      for (int i = 0; i < 4; ++i)
#pragma unroll
        for (int j = 0; j < 4; ++j)
          acc[i][j] = __builtin_amdgcn_mfma_f32_16x16x32_bf16(af[i], bg[j], acc[i][j], 0, 0, 0);

      __syncthreads();
    }
  }

  // epilogue: C/D layout col = lane&15, row = (lane>>4)*4 + reg  [m89-verified]
#pragma unroll
  for (int i = 0; i < 4; ++i) {
    int r0 = brow + wr * 64 + i * 16 + lk * 4;
#pragma unroll
    for (int j = 0; j < 4; ++j) {
      int col = bcol + wc * 64 + j * 16 + lr;
#pragma unroll
      for (int r = 0; r < 4; ++r)
        C[(size_t)(r0 + r) * NDIM + col] = acc[i][j][r];
    }
  }
}

// ---------------- fallback (only if ws too small): naive fp32 ---------------
__global__ void fallback_fp32(const float* __restrict__ x,
                              const float* __restrict__ f,
                              float* __restrict__ out) {
  __shared__ float xs[KIN + 3];
  int b = blockIdx.y;
  for (int k = threadIdx.x; k < KIN; k += 256) xs[k] = x[(size_t)b * KIN + k];
  __syncthreads();
  int o = blockIdx.x * 256 + threadIdx.x;
  const float* fr = f + (size_t)o * KIN;
  float s = 0.f;
  for (int k = 0; k < KIN; ++k) s += xs[k] * fr[k];
  out[(size_t)b * NDIM + o] = s;
}

// ---------------- launch ----------------------------------------------------
extern "C" void kernel_launch(void* const* d_in, const int* in_sizes, int n_in,
                              void* d_out, int out_size, void* d_ws, size_t ws_size,
                              hipStream_t stream) {
  const float* x  = (const float*)d_in[0];
  const float* fr = (const float*)d_in[1];
  // d_in[2] = filters_imag: provably unused
  float* out = (float*)d_out;

  const size_t elemsA = (size_t)MDIM * KPAD;
  const size_t elemsB = (size_t)NDIM * KPAD;
  const size_t need   = (2 * elemsA + 2 * elemsB) * sizeof(bf16);

  if (ws_size < need) {
    fallback_fp32<<<dim3(NDIM / 256, MDIM), dim3(256), 0, stream>>>(x, fr, out);
    return;
  }

  bf16* A_hi = (bf16*)d_ws;
  bf16* A_lo = A_hi + elemsA;
  bf16* B_hi = A_lo + elemsA;
  bf16* B_lo = B_hi + elemsB;

  dim3 blk(256);
  split_hilo<<<dim3((KPAD / 4 + 255) / 256, MDIM), blk, 0, stream>>>(x, A_hi, A_lo);
  split_hilo<<<dim3((KPAD / 4 + 255) / 256, NDIM), blk, 0, stream>>>(fr, B_hi, B_lo);

  gemm_split<<<dim3((MDIM / BM) * (NDIM / BN)), blk, 0, stream>>>(A_hi, A_lo, B_hi, B_lo, out);
}

// Round 4
// 336.414 us; speedup vs baseline: 2.2997x; 2.2997x over previous
//
#include <hip/hip_runtime.h>
#include <hip/hip_bf16.h>
#include <hip/hip_fp16.h>
#include <stdint.h>

// C[8192,4096] = x[8192,2049] @ filters_real[4096,2049]^T  (fp32 out)
// filters_imag provably dead: Re(x*(a+bi)) = x*a for real x.
// fp16 single GEMM (fp32 acc): err std 4.5e-4 << reference's own 2.5e-3 noise.
//
// 256x256x64 8-phase schedule (T1 XCD-swizzle + T2 LDS XOR-swizzle +
// T3/T4 counted-vmcnt pipeline + T5 setprio), plain HIP per m201 template.
// 8 waves (2Mx4N), per-wave 128x64 out = acc[8][4] f32x4.
// LDS 128 KiB dynamic: [buf2][A/B][256r][64k] fp16, rows 128B.
// Swizzle: byte ^= ((row&7)<<4) — applied on global SOURCE (inverse) +
// ds_read addr; global_load_lds dest stays linear (rule #21).

#define KIN   2049
#define KPAD  2112            // 33 * 64
#define MDIM  8192
#define NDIM  4096
#define BM    256
#define BN    256
#define BK    64
#define NT    (KPAD / BK)     // 33

typedef _Float16 f16x8 __attribute__((ext_vector_type(8)));
typedef float    f32x4 __attribute__((ext_vector_type(4)));

// ---------------- prep: fp32 -> fp16, zero-padded to KPAD -------------------
__global__ __launch_bounds__(256) void cvt_f16(const float* __restrict__ xsrc,
                                               const float* __restrict__ fsrc,
                                               _Float16* __restrict__ xa,
                                               _Float16* __restrict__ fb) {
  int r = blockIdx.x;
  const float* src;
  _Float16* dst;
  if (r < MDIM) { src = xsrc + (size_t)r * KIN;          dst = xa + (size_t)r * KPAD; }
  else          { src = fsrc + (size_t)(r - MDIM) * KIN; dst = fb + (size_t)(r - MDIM) * KPAD; }
  int t = threadIdx.x;
#pragma unroll
  for (int u = 0; u < 8; ++u) {
    int c = t + u * 256;               // 0..2047 coalesced
    dst[c] = (_Float16)src[c];
  }
  if (t < 8) {                         // cols 2048..2111
    f16x8 v = {};
    if (t == 0) v[0] = (_Float16)src[2048];
    *reinterpret_cast<f16x8*>(&dst[2048 + t * 8]) = v;   // 16B aligned
  }
}

// ---------------- 256^2 8-phase GEMM ----------------------------------------
#define GLDS(SRC, DSTOFF)                                                      \
  __builtin_amdgcn_global_load_lds(                                            \
      (const __attribute__((address_space(1))) void*)(SRC),                    \
      (__attribute__((address_space(3))) void*)(lds + (DSTOFF)), 16, 0, 0)

// KC in elements. Halves are 128 rows (=16384 B in LDS, 128*KPAD elems global).
#define STAGE_A(BUF, HALF, KC) do {                                            \
  GLDS(Asrc0 + (size_t)(HALF) * 128 * KPAD + (KC), (BUF)*65536 + (HALF)*16384 + dst0); \
  GLDS(Asrc1 + (size_t)(HALF) * 128 * KPAD + (KC), (BUF)*65536 + (HALF)*16384 + dst1); \
} while (0)
#define STAGE_B(BUF, HALF, KC) do {                                            \
  GLDS(Bsrc0 + (size_t)(HALF) * 128 * KPAD + (KC), (BUF)*65536 + 32768 + (HALF)*16384 + dst0); \
  GLDS(Bsrc1 + (size_t)(HALF) * 128 * KPAD + (KC), (BUF)*65536 + 32768 + (HALF)*16384 + dst1); \
} while (0)

#define LDA(BUF, QR, AF) do {                                                  \
  int rb_ = (wr * 128 + (QR) * 64 + lr) * 128 + (BUF) * 65536;                 \
  _Pragma("unroll") for (int i = 0; i < 4; ++i) {                              \
    AF[i][0] = *(const f16x8*)(lds + rb_ + i * 2048 + c0);                     \
    AF[i][1] = *(const f16x8*)(lds + rb_ + i * 2048 + c1);                     \
  } } while (0)
#define LDB(BUF, QC, BF) do {                                                  \
  int rb_ = (wc * 64 + (QC) * 32 + lr) * 128 + (BUF) * 65536 + 32768;          \
  _Pragma("unroll") for (int j = 0; j < 2; ++j) {                              \
    BF[j][0] = *(const f16x8*)(lds + rb_ + j * 2048 + c0);                     \
    BF[j][1] = *(const f16x8*)(lds + rb_ + j * 2048 + c1);                     \
  } } while (0)

#define MM(QR, QC, AF, BF) do {                                                \
  __builtin_amdgcn_s_setprio(1);                                               \
  _Pragma("unroll") for (int s = 0; s < 2; ++s)                                \
  _Pragma("unroll") for (int i = 0; i < 4; ++i)                                \
  _Pragma("unroll") for (int j = 0; j < 2; ++j)                                \
    acc[(QR)*4 + i][(QC)*2 + j] = __builtin_amdgcn_mfma_f32_16x16x32_f16(      \
        AF[i][s], BF[j][s], acc[(QR)*4 + i][(QC)*2 + j], 0, 0, 0);             \
  __builtin_amdgcn_s_setprio(0);                                               \
} while (0)

#define BAR() __builtin_amdgcn_s_barrier()

__global__ __launch_bounds__(512, 2) void gemm8_f16(
    const _Float16* __restrict__ A, const _Float16* __restrict__ B,
    float* __restrict__ C) {
  extern __shared__ char lds[];   // 131072 B: [buf][A|B][256][64] f16

  // T1: XCD-bijective swizzle; 512 blocks = 8 XCDs x 64
  int wg  = blockIdx.x;
  int swz = (wg & 7) * 64 + (wg >> 3);
  int brow = (swz >> 4) * BM;     // 32 m-tiles
  int bcol = (swz & 15) * BN;     // 16 n-tiles

  int tid  = threadIdx.x;
  int lane = tid & 63;
  int wid  = tid >> 6;
  int wr = wid >> 2, wc = wid & 3;     // 2x4 wave grid; wave tile 128x64
  int lr = lane & 15, lk = lane >> 4;

  // T2 swizzle constants (read side): byte ^= ((row&7)<<4); row&7 == lr&7
  int sx = (lr & 7) << 4;
  int c0 = (lk * 16) ^ sx;        // kstep 0
  int c1 = (64 + lk * 16) ^ sx;   // kstep 1

  // staging addresses: load l covers elems (l*512+tid)*8 of a 128x64 half-tile
  int d0e = tid * 8,         ri0 = d0e >> 6, cb0 = (d0e & 63) * 2;
  int d1e = (512 + tid) * 8, ri1 = d1e >> 6, cb1 = (d1e & 63) * 2;
  int sc0 = cb0 ^ ((ri0 & 7) << 4);    // inverse-swizzled source col (bytes)
  int sc1 = cb1 ^ ((ri1 & 7) << 4);
  const _Float16* Asrc0 = A + (size_t)(brow + ri0) * KPAD + sc0 / 2;
  const _Float16* Asrc1 = A + (size_t)(brow + ri1) * KPAD + sc1 / 2;
  const _Float16* Bsrc0 = B + (size_t)(bcol + ri0) * KPAD + sc0 / 2;
  const _Float16* Bsrc1 = B + (size_t)(bcol + ri1) * KPAD + sc1 / 2;
  int dst0 = tid * 16;            // linear LDS dest (bytes) for load 0
  int dst1 = 8192 + tid * 16;     // load 1

  f32x4 acc[8][4] = {};
  f16x8 af[4][2], b0[2][2], b1[2][2];

  // prologue: tile0 all 4 halves (buf0), then tile1 A0,B0 (buf1) -> 12 loads
  STAGE_A(0, 0, 0); STAGE_A(0, 1, 0); STAGE_B(0, 0, 0); STAGE_B(0, 1, 0);
  STAGE_A(1, 0, BK); STAGE_B(1, 0, BK);
  asm volatile("s_waitcnt vmcnt(4)" ::: "memory");   // tile0's 8 loads done
  BAR();
  __builtin_amdgcn_sched_barrier(0);

  for (int kt = 0; kt < NT; ++kt) {
    const int buf = kt & 1, obuf = buf ^ 1;
    // ---- ph0: A qr0 + B qc0 reads; stage A-half1(kt+1)
    LDA(buf, 0, af); LDB(buf, 0, b0);
    if (kt + 1 < NT) STAGE_A(obuf, 1, (size_t)(kt + 1) * BK);
    BAR();
    MM(0, 0, af, b0);
    BAR();
    // ---- ph1: B qc1 reads; stage B-half1(kt+1)
    LDB(buf, 1, b1);
    if (kt + 1 < NT) STAGE_B(obuf, 1, (size_t)(kt + 1) * BK);
    BAR();
    MM(0, 1, af, b1);
    BAR();
    // ---- ph2: A qr1 reads; stage B-half0(kt+2) (same buf: B reads done ph1)
    LDA(buf, 1, af);
    if (kt + 2 < NT) STAGE_B(buf, 0, (size_t)(kt + 2) * BK);
    BAR();
    MM(1, 0, af, b0);
    BAR();
    // ---- ph3: no reads; stage A-half0(kt+2) (A reads done ph2)
    if (kt + 2 < NT) STAGE_A(buf, 0, (size_t)(kt + 2) * BK);
    BAR();
    MM(1, 1, af, b1);
    // ---- K-tile boundary: counted vmcnt (outstanding = 2 halves of kt+2)
    if (kt < NT - 1) {
      if (kt + 1 == NT - 1) asm volatile("s_waitcnt vmcnt(0)" ::: "memory");
      else                  asm volatile("s_waitcnt vmcnt(4)" ::: "memory");
    }
    BAR();
    __builtin_amdgcn_sched_barrier(0);
  }

  // epilogue: C/D layout col = lane&15, row = (lane>>4)*4 + reg [m89-verified]
#pragma unroll
  for (int i = 0; i < 8; ++i) {
    int r0 = brow + wr * 128 + i * 16 + lk * 4;
#pragma unroll
    for (int j = 0; j < 4; ++j) {
      int col = bcol + wc * 64 + j * 16 + lr;
#pragma unroll
      for (int r = 0; r < 4; ++r)
        C[(size_t)(r0 + r) * NDIM + col] = acc[i][j][r];
    }
  }
}

// ---------------- fallback (ws too small): naive fp32 -----------------------
__global__ void fallback_fp32(const float* __restrict__ x,
                              const float* __restrict__ f,
                              float* __restrict__ out) {
  __shared__ float xs[KIN + 3];
  int b = blockIdx.y;
  for (int k = threadIdx.x; k < KIN; k += 256) xs[k] = x[(size_t)b * KIN + k];
  __syncthreads();
  int o = blockIdx.x * 256 + threadIdx.x;
  const float* fr = f + (size_t)o * KIN;
  float s = 0.f;
  for (int k = 0; k < KIN; ++k) s += xs[k] * fr[k];
  out[(size_t)b * NDIM + o] = s;
}

// ---------------- launch ----------------------------------------------------
extern "C" void kernel_launch(void* const* d_in, const int* in_sizes, int n_in,
                              void* d_out, int out_size, void* d_ws, size_t ws_size,
                              hipStream_t stream) {
  const float* x  = (const float*)d_in[0];
  const float* fr = (const float*)d_in[1];
  float* out = (float*)d_out;

  const size_t elemsA = (size_t)MDIM * KPAD;
  const size_t elemsB = (size_t)NDIM * KPAD;
  const size_t need   = (elemsA + elemsB) * sizeof(_Float16);

  if (ws_size < need) {
    fallback_fp32<<<dim3(NDIM / 256, MDIM), dim3(256), 0, stream>>>(x, fr, out);
    return;
  }

  _Float16* Ah = (_Float16*)d_ws;
  _Float16* Bh = Ah + elemsA;

  static bool attr_set = false;   // host-side only; same work every call
  if (!attr_set) {
    hipFuncSetAttribute((const void*)gemm8_f16,
                        hipFuncAttributeMaxDynamicSharedMemorySize, 131072);
    attr_set = true;
  }

  cvt_f16<<<dim3(MDIM + NDIM), dim3(256), 0, stream>>>(x, fr, Ah, Bh);
  gemm8_f16<<<dim3((MDIM / BM) * (NDIM / BN)), dim3(512), 131072, stream>>>(Ah, Bh, out);
}